// Round 13
// baseline (133.872 us; speedup 1.0000x reference)
//
#include <hip/hip_runtime.h>

// TwoTwoNet: rank-2 recurrence collapse, round 12.
// R11 lesson: data is in the saturated regime -> clip-bypass guard removed.
// R12 change: split the monolithic reduce so dependency stalls are filled:
//   inner(p1,p2; mm kept live) -> [A: 12 DPP q-chains] -> po-fmas (filler)
//   -> [B: readlane q1,q2 (pinned after po via dummy dep)] -> al/be(t+1)
//   -> [C: 6 DPP ho chain] -> lane-63 direct store (no 3rd readlane).
// Next step's inner fills C's percolation latency (it only needs q1,q2).
// Math (verified R3-R11): alpha_t = q1 + x_t*A1, beta_t = q2 + x_t*A2,
//   m = clip(alpha*d + beta*e, -1, 1); q1' = <m,g1>, q2' = <m,g2>,
//   out_t = <m,wo>; g1 = w00*mask*d + w01*mask*e, g2 = w10*mask*d + w11*mask*e.

typedef float f32x2 __attribute__((ext_vector_type(2)));

constexpr int Bc = 256;
constexpr int Tc = 512;
constexpr int CH = Tc / 64;   // 8 chunks of 64 steps

__device__ __forceinline__ float readlane_f(float v, int l) {
    return __int_as_float(__builtin_amdgcn_readlane(__float_as_int(v), l));
}

__device__ __forceinline__ f32x2 pk_fma(f32x2 a, f32x2 b, f32x2 c) {
    f32x2 d;
    asm("v_pk_fma_f32 %0, %1, %2, %3" : "=v"(d) : "v"(a), "v"(b), "v"(c));
    return d;
}
__device__ __forceinline__ f32x2 pk_mul(f32x2 a, f32x2 b) {
    f32x2 d;
    asm("v_pk_mul_f32 %0, %1, %2" : "=v"(d) : "v"(a), "v"(b));
    return d;
}

// Block A: 2 interleaved DPP chains (q1,q2), s_nop-padded for the 2-wait-state
// DPP read-after-VALU hazard. po accumulators pass through as dummy inouts so
// the po fmas are pinned AFTER this block (they fill its percolation latency).
#define DPP2(lvl, msk)                                                                              \
        "v_add_f32_dpp %[a], %[a], %[a] " lvl " row_mask:" msk " bank_mask:0xf bound_ctrl:1\n\t"    \
        "v_add_f32_dpp %[b], %[b], %[b] " lvl " row_mask:" msk " bank_mask:0xf bound_ctrl:1\n\t"    \
        "s_nop 0\n\t"

#define REDUCE_Q(h1, h2, poa, pob)                                                                  \
    asm volatile("s_nop 1\n\t"                                                                      \
        DPP2("row_shr:1",   "0xf")                                                                  \
        DPP2("row_shr:2",   "0xf")                                                                  \
        DPP2("row_shr:4",   "0xf")                                                                  \
        DPP2("row_shr:8",   "0xf")                                                                  \
        DPP2("row_bcast:15","0xa")                                                                  \
        DPP2("row_bcast:31","0xc")                                                                  \
        "s_nop 0"                                                                                   \
        : [a] "+v"(h1), [b] "+v"(h2), [pa] "+v"(poa), [pb] "+v"(pob))

// Block B: readlane q totals; dummy input `dep` (final po) pins it after the
// po filler pass. h1/h2 were last written ~10 instrs ago -> hazard clear.
#define READ_Q(h1, h2, s1, s2, dep)                                                                 \
    asm volatile(                                                                                   \
        "v_readlane_b32 %[x], %[a], 63\n\t"                                                         \
        "v_readlane_b32 %[y], %[b], 63"                                                             \
        : [x] "=s"(s1), [y] "=s"(s2)                                                                \
        : [a] "v"(h1), [b] "v"(h2), [d] "v"(dep))

// Block C: single DPP chain for the out dot; total lands in lane 63.
#define DPP1(lvl, msk)                                                                              \
        "v_add_f32_dpp %[a], %[a], %[a] " lvl " row_mask:" msk " bank_mask:0xf bound_ctrl:1\n\t"    \
        "s_nop 1\n\t"

#define REDUCE_O(h)                                                                                 \
    asm volatile("s_nop 1\n\t"                                                                      \
        DPP1("row_shr:1",   "0xf")                                                                  \
        DPP1("row_shr:2",   "0xf")                                                                  \
        DPP1("row_shr:4",   "0xf")                                                                  \
        DPP1("row_shr:8",   "0xf")                                                                  \
        DPP1("row_bcast:15","0xa")                                                                  \
        DPP1("row_bcast:31","0xc")                                                                  \
        : [a] "+v"(h))

#define DECL_TBL(i) f32x2 d2_##i, e2_##i, g1_##i, g2_##i, wo_##i

#define INIT_TBL(i) do { \
    _Pragma("unroll") \
    for (int h = 0; h < 2; ++h) { \
        const int c = lane + 64 * (2 * (i) + h); \
        const float dv   = dec_orth[c]; \
        const float ev   = enc_orth[c]; \
        const float mv   = mask[c]; \
        const float encv = encoder[c]; \
        const float decv = decoder[c]; \
        const float s0v  = state0[c]; \
        const float mdv = mv * dv, mev = mv * ev; \
        d2_##i[h]  = dv;  e2_##i[h]  = ev; \
        g1_##i[h] = fmaf(w00, mdv, w01 * mev); \
        g2_##i[h] = fmaf(w10, mdv, w11 * mev); \
        wo_##i[h] = mv * decv; \
        s0d += s0v * dv;  s0e += s0v * ev; \
        kd = fmaf(mv * encv, dv, kd); \
        ke = fmaf(mv * encv, ev, ke); \
    } \
} while (0)

// Inner pass (per channel pair): tt, clip, accumulate p1,p2; mm stays live.
#define ACC_P(i) do { \
    f32x2 tt = pk_fma(b2, e2_##i, pk_mul(a2, d2_##i)); \
    mm_##i.x = __builtin_amdgcn_fmed3f(tt.x, -1.0f, 1.0f); \
    mm_##i.y = __builtin_amdgcn_fmed3f(tt.y, -1.0f, 1.0f); \
    p1 = pk_fma(mm_##i, g1_##i, p1); \
    p2 = pk_fma(mm_##i, g2_##i, p2); \
} while (0)

__global__ __attribute__((amdgpu_waves_per_eu(1, 1))) __launch_bounds__(64)
void twotwonet_kernel(
    const float* __restrict__ x,        // [B, T]
    const float* __restrict__ state0,   // [n]
    const float* __restrict__ mask,     // [n]
    const float* __restrict__ w,        // [2,2]
    const float* __restrict__ dec_orth, // [n]
    const float* __restrict__ enc_orth, // [n]
    const float* __restrict__ decoder,  // [n]
    const float* __restrict__ encoder,  // [n]
    float* __restrict__ out)            // [B, T]
{
    const int b    = blockIdx.x;
    const int lane = threadIdx.x;   // 0..63

    const float w00 = w[0], w01 = w[1], w10 = w[2], w11 = w[3];

    DECL_TBL(0); DECL_TBL(1); DECL_TBL(2); DECL_TBL(3);
    DECL_TBL(4); DECL_TBL(5); DECL_TBL(6); DECL_TBL(7);

    float s0d = 0.f, s0e = 0.f, kd = 0.f, ke = 0.f;
    INIT_TBL(0); INIT_TBL(1); INIT_TBL(2); INIT_TBL(3);
    INIT_TBL(4); INIT_TBL(5); INIT_TBL(6); INIT_TBL(7);

    // cold-path init reduce (runs once)
#pragma unroll
    for (int m = 32; m >= 1; m >>= 1) {
        s0d += __shfl_xor(s0d, m, 64);
        s0e += __shfl_xor(s0e, m, 64);
        kd  += __shfl_xor(kd, m, 64);
        ke  += __shfl_xor(ke, m, 64);
    }

    const float A1 = fmaf(w00, kd, w01 * ke);   // x-coupling for alpha
    const float A2 = fmaf(w10, kd, w11 * ke);   // x-coupling for beta

    // Preload this batch's x row prescaled by A1/A2 (al = q1 + xr1 etc).
    const float* xrow = x + (size_t)b * Tc;
    float xr1[CH], xr2[CH];
#pragma unroll
    for (int c = 0; c < CH; ++c) {
        const float xv = xrow[lane + 64 * c];
        xr1[c] = xv * A1;
        xr2[c] = xv * A2;
    }

    // Carried state (wave-uniform): q1 = w00*Sd + w01*Se, q2 = w10*Sd + w11*Se
    float q1 = fmaf(w00, s0d, w01 * s0e);
    float q2 = fmaf(w10, s0d, w11 * s0e);

    float* outrow = out + (size_t)b * Tc;

#pragma unroll
    for (int c = 0; c < CH; ++c) {
#pragma unroll 2
        for (int t2 = 0; t2 < 64; ++t2) {
            const float al = q1 + readlane_f(xr1[c], t2);
            const float be = q2 + readlane_f(xr2[c], t2);
            const f32x2 a2 = {al, al};
            const f32x2 b2 = {be, be};

            f32x2 mm_0, mm_1, mm_2, mm_3, mm_4, mm_5, mm_6, mm_7;
            f32x2 p1 = {0.f, 0.f}, p2 = {0.f, 0.f};
            ACC_P(0); ACC_P(1); ACC_P(2); ACC_P(3);
            ACC_P(4); ACC_P(5); ACC_P(6); ACC_P(7);

            float h1 = p1.x + p1.y;
            float h2 = p2.x + p2.y;

            // Block A: q-chains percolate ...
            f32x2 poa = {0.f, 0.f}, pob = {0.f, 0.f};
            REDUCE_Q(h1, h2, poa, pob);

            // ... while the out-dot fmas issue (filler work).
            poa = pk_fma(mm_0, wo_0, poa);  pob = pk_fma(mm_1, wo_1, pob);
            poa = pk_fma(mm_2, wo_2, poa);  pob = pk_fma(mm_3, wo_3, pob);
            poa = pk_fma(mm_4, wo_4, poa);  pob = pk_fma(mm_5, wo_5, pob);
            poa = pk_fma(mm_6, wo_6, poa);  pob = pk_fma(mm_7, wo_7, pob);
            const f32x2 pos = poa + pob;

            // Block B: read q totals (pinned after the filler via dep=pos).
            float r1, r2;
            READ_Q(h1, h2, r1, r2, pos);
            q1 = r1;
            q2 = r2;

            // Block C: out-chain percolates; next step's inner (needs only
            // q1,q2) issues during its latency.
            float ho = pos.x + pos.y;
            REDUCE_O(ho);

            if (lane == 63) outrow[64 * c + t2] = ho;
        }
    }
}

extern "C" void kernel_launch(void* const* d_in, const int* in_sizes, int n_in,
                              void* d_out, int out_size, void* d_ws, size_t ws_size,
                              hipStream_t stream) {
    const float* x        = (const float*)d_in[0];
    const float* state0   = (const float*)d_in[1];
    const float* mask     = (const float*)d_in[2];
    const float* w        = (const float*)d_in[3];
    const float* dec_orth = (const float*)d_in[4];
    const float* enc_orth = (const float*)d_in[5];
    const float* decoder  = (const float*)d_in[6];
    const float* encoder  = (const float*)d_in[7];
    float* out = (float*)d_out;

    twotwonet_kernel<<<dim3(Bc), dim3(64), 0, stream>>>(
        x, state0, mask, w, dec_orth, enc_orth, decoder, encoder, out);
}